// Round 6
// baseline (123.543 us; speedup 1.0000x reference)
//
#include <hip/hip_runtime.h>

static constexpr int C    = 64;
static constexpr int H    = 128;
static constexpr int W    = 128;
static constexpr int NPIX = H * W;      // 16384
static constexpr int PAD  = 3;          // WS=7 -> +-3

// ---------------------------------------------------------------------------
// 1) conv1x1 — round-1 exact (part of proven 123.5 config). Each wave:
//    64 pixels x 8 output channels; xr[64] resident under (256,4).
//    grid (NPIX/64, 2, 3) = 1536 blocks -> 6 blocks/CU.
//    NOTE (r4): W-in-LDS broadcast variant regressed (52 us). Keep W on SMEM.
// ---------------------------------------------------------------------------
__global__ __launch_bounds__(256, 4) void k_conv(
    const float* __restrict__ x,
    const float* __restrict__ Wq, const float* __restrict__ bq,
    const float* __restrict__ Wk, const float* __restrict__ bk,
    const float* __restrict__ Wv, const float* __restrict__ bv,
    float* __restrict__ qT, float* __restrict__ ko, float* __restrict__ vo)
{
    const int tid  = threadIdx.x;
    const int lane = tid & 63;
    const int p    = blockIdx.x * 64 + lane;
    const int o0   = __builtin_amdgcn_readfirstlane(
                         blockIdx.y * 32 + (tid >> 6) * 8);
    const int z    = blockIdx.z;
    const float* Wm = (z == 0) ? Wq : (z == 1) ? Wk : Wv;
    const float* bm = (z == 0) ? bq : (z == 1) ? bk : bv;

    float xr[C];
#pragma unroll
    for (int c = 0; c < C; ++c) xr[c] = x[c * NPIX + p];

    float acc[8];
#pragma unroll
    for (int j = 0; j < 8; ++j) acc[j] = bm[o0 + j];

#pragma unroll
    for (int c = 0; c < C; ++c) {
        const float xv = xr[c];
#pragma unroll
        for (int j = 0; j < 8; ++j)
            acc[j] += Wm[(o0 + j) * C + c] * xv;
    }

    if (z == 0) {
        *(float4*)(qT + (size_t)p * C + o0) =
            make_float4(acc[0], acc[1], acc[2], acc[3]);
        *(float4*)(qT + (size_t)p * C + o0 + 4) =
            make_float4(acc[4], acc[5], acc[6], acc[7]);
    } else {
        float* outm = (z == 1) ? ko : vo;
#pragma unroll
        for (int j = 0; j < 8; ++j)
            outm[(o0 + j) * NPIX + p] = acc[j];
    }
}

// ---------------------------------------------------------------------------
// 2) merged dispatch: [gram+diag] (blocks 0..1023) and [7x7 box of v]
//    (blocks 1024..1535). block 256, (256,3) for the 2-kk gram tiling.
//    GRAM CHANGE (this round's single variable): each thread holds TWO
//    k-columns (kk = kkt, kkt+64) in VGPRs (~128) and covers ~6 rows
//    (4 row-groups of 64 kk-threads). Every broadcast q float4 now feeds
//    8 MACs (was 4): gram j-loop LDS b128 wave-insts 704 -> 352 per block.
//    Diag phase / box half / Sl layout unchanged.
// ---------------------------------------------------------------------------
__global__ __launch_bounds__(256, 3) void k_mid(
    const float* __restrict__ qT, const float* __restrict__ kmat,
    const float* __restrict__ v,
    float* __restrict__ Sd, float* __restrict__ Vs)
{
    __shared__ union {
        struct { float Sl[22][130]; float qs[22][64]; } g;   // 16.7 KB
        struct { float vt[22][128]; float vh[22][128]; } box; // 22.5 KB
    } u;
    const int bid = blockIdx.x;
    const int tid = threadIdx.x;

    if (bid < 1024) {
        // ----- fused row-Gram + diagonal 7-sum -----
        const int h   = bid >> 3;
        const int w0  = (bid & 7) * 16;

        // stage q rows w0-3 .. w0+18 (zero-filled outside [0,W))
        for (int i = tid; i < 22 * 16; i += 256) {
            int r  = i >> 4, c4 = (i & 15) << 2;
            int wp = w0 - 3 + r;
            float4 qv = make_float4(0.f, 0.f, 0.f, 0.f);
            if (wp >= 0 && wp < W)
                qv = *(const float4*)(qT + (size_t)(h * W + wp) * C + c4);
            *(float4*)(&u.g.qs[r][c4]) = qv;
        }

        // two k-columns per thread: kkt and kkt+64 (coalesced loads)
        const int kkt = tid & 63;
        const int g   = tid >> 6;            // 0..3, wave-uniform row group
        float ks0[C], ks1[C];
#pragma unroll
        for (int c = 0; c < C; ++c) {
            ks0[c] = kmat[c * NPIX + h * W + kkt];
            ks1[c] = kmat[c * NPIX + h * W + kkt + 64];
        }
        __syncthreads();

        for (int j = 0; j < 6; ++j) {
            int row = g * 6 + j;             // 0..23, wave-uniform
            if (row < 22) {                  // wave-uniform branch
                float a0 = 0.f, a1 = 0.f, a2 = 0.f, a3 = 0.f;
                float b0 = 0.f, b1 = 0.f, b2 = 0.f, b3 = 0.f;
#pragma unroll
                for (int c = 0; c < C; c += 4) {
                    float4 qv = *(const float4*)(&u.g.qs[row][c]); // broadcast
                    a0 += qv.x * ks0[c + 0];  b0 += qv.x * ks1[c + 0];
                    a1 += qv.y * ks0[c + 1];  b1 += qv.y * ks1[c + 1];
                    a2 += qv.z * ks0[c + 2];  b2 += qv.z * ks1[c + 2];
                    a3 += qv.w * ks0[c + 3];  b3 += qv.w * ks1[c + 3];
                }
                u.g.Sl[row][kkt]      = (a0 + a1) + (a2 + a3);
                u.g.Sl[row][kkt + 64] = (b0 + b1) + (b2 + b3);
            }
        }
        __syncthreads();

        // ----- diagonal 7-sum (unchanged) -----
        const int kk  = tid & 127;
        const int wsl = tid >> 7;            // 0/1, wave-uniform
#pragma unroll
        for (int r = 0; r < 8; ++r) {
            int wl = wsl * 8 + r;            // 0..15
            float a = 0.f;
#pragma unroll
            for (int dd = -PAD; dd <= PAD; ++dd) {
                int kj = kk + dd;
                if (kj >= 0 && kj < W)
                    a += u.g.Sl[wl + 3 + dd][kj];
            }
            Sd[(size_t)(h * W + w0 + wl) * W + kk] = a;
        }
    } else {
        // ----- 7x7 box sum of v (separable in LDS, unchanged) -----
        const int b2 = bid - 1024;           // 0..511
        const int c  = b2 >> 3;              // 0..63
        const int h0 = (b2 & 7) * 16;

        for (int i = tid; i < 22 * 128; i += 256) {
            int r = i >> 7, w = i & 127;
            int h = h0 - 3 + r;
            u.box.vt[r][w] = (h >= 0 && h < H) ? v[c * NPIX + h * W + w] : 0.f;
        }
        __syncthreads();
        for (int i = tid; i < 22 * 128; i += 256) {
            int r = i >> 7, w = i & 127;
            float s = 0.f;
#pragma unroll
            for (int d = -PAD; d <= PAD; ++d) {
                int wj = w + d;
                if (wj >= 0 && wj < W) s += u.box.vt[r][wj];
            }
            u.box.vh[r][w] = s;
        }
        __syncthreads();
        for (int i = tid; i < 16 * 128; i += 256) {
            int r = i >> 7, w = i & 127;
            float s = 0.f;
#pragma unroll
            for (int d = 0; d < 7; ++d) s += u.box.vh[r + d][w];
            Vs[c * NPIX + (h0 + r) * W + w] = s;
        }
    }
}

// ---------------------------------------------------------------------------
// 3) FUSED vertical-7-sum + softmax + PV, 1024-thread version (round-5
//    exact). grid (H, 2) = 256 blocks x 1024 thr; 2 blocks/CU x 16 waves =
//    32 waves/CU. One barrier. LDS 65.8 KB.
// ---------------------------------------------------------------------------
__global__ __launch_bounds__(1024, 4) void k_fused(
    const float* __restrict__ Sd, const float* __restrict__ Vs,
    float* __restrict__ out)
{
    constexpr int AP = 129;          // attn LDS pitch
    __shared__ float At[64][AP];     // attn[w-local][kk], 33.0 KB
    __shared__ float Vl[64][128];    // Vs[c][kk],         32.8 KB

    const int h   = blockIdx.x;
    const int w0  = blockIdx.y * 64;
    const int tid = threadIdx.x;

    // ---- issue Vs staging loads early (consumed after phase A) ----
    float4 vstage[2];
#pragma unroll
    for (int r = 0; r < 2; ++r) {
        int L  = tid + r * 1024;         // 0..2047 float4 tiles
        int c  = L >> 5;                 // 32 float4 per channel row
        int k4 = (L & 31) << 2;
        vstage[r] = *(const float4*)(Vs + (size_t)c * NPIX + h * W + k4);
    }

    // ---- phase A: logits (vertical 7-sum of Sd) + softmax into LDS ----
    const int wl = tid >> 4;             // 0..63 (w within half)
    const int s  = tid & 15;             // kk-16th: kk = s*8 + e

    float4 g0 = make_float4(0.f, 0.f, 0.f, 0.f);
    float4 g1 = g0;
#pragma unroll
    for (int i = 0; i < 7; ++i) {
        int hp = h - 3 + i;              // block-uniform branch
        if (hp >= 0 && hp < H) {
            const float4* src = (const float4*)(
                Sd + (size_t)hp * NPIX + (w0 + wl) * W + s * 8);
            float4 a = src[0], b = src[1];
            g0.x += a.x; g0.y += a.y; g0.z += a.z; g0.w += a.w;
            g1.x += b.x; g1.y += b.y; g1.z += b.z; g1.w += b.w;
        }
    }

    float lg[8] = { g0.x, g0.y, g0.z, g0.w,  g1.x, g1.y, g1.z, g1.w };

    float m = lg[0];
#pragma unroll
    for (int e = 1; e < 8; ++e) m = fmaxf(m, lg[e]);
#pragma unroll
    for (int off = 1; off <= 8; off <<= 1) m = fmaxf(m, __shfl_xor(m, off));

    float ssum = 0.f;
#pragma unroll
    for (int e = 0; e < 8; ++e) { lg[e] = __expf(lg[e] - m); ssum += lg[e]; }
#pragma unroll
    for (int off = 1; off <= 8; off <<= 1) ssum += __shfl_xor(ssum, off);
    const float inv = 1.f / ssum;

#pragma unroll
    for (int e = 0; e < 8; ++e) At[wl][s * 8 + e] = lg[e] * inv;

    // ---- land Vs into LDS, sync ----
#pragma unroll
    for (int r = 0; r < 2; ++r) {
        int L  = tid + r * 1024;
        int c  = L >> 5;
        int k4 = (L & 31) << 2;
        *(float4*)(&Vl[c][k4]) = vstage[r];
    }
    __syncthreads();

    // ---- phase B: out[c, h, w0+w2] = sum_kk At[w2][kk] * Vl[c][kk] ----
    const int w2 = tid & 63;
    const int c0 = __builtin_amdgcn_readfirstlane((tid >> 6) * 4);

    float acc[4];
#pragma unroll
    for (int j = 0; j < 4; ++j) acc[j] = 0.f;

    for (int kk = 0; kk < 128; kk += 4) {
        float4 a = *(const float4*)(&At[w2][kk]);
#pragma unroll
        for (int j = 0; j < 4; ++j) {
            float4 vv = *(const float4*)(&Vl[c0 + j][kk]);   // broadcast
            acc[j] += a.x * vv.x + a.y * vv.y + a.z * vv.z + a.w * vv.w;
        }
    }

#pragma unroll
    for (int j = 0; j < 4; ++j)
        out[(size_t)(c0 + j) * NPIX + h * W + w0 + w2] = acc[j];
}

// ---------------------------------------------------------------------------
// Workspace: 6M floats = 24 MB used, non-overlapping:
//   qT [0,1M)  k [1M,2M)  v [2M,3M)  Sd [3M,5M)  Vs [5M,6M)
// ---------------------------------------------------------------------------
extern "C" void kernel_launch(void* const* d_in, const int* in_sizes, int n_in,
                              void* d_out, int out_size, void* d_ws, size_t ws_size,
                              hipStream_t stream)
{
    const float* x  = (const float*)d_in[0];
    const float* Wq = (const float*)d_in[1];
    const float* bq = (const float*)d_in[2];
    const float* Wk = (const float*)d_in[3];
    const float* bk = (const float*)d_in[4];
    const float* Wv = (const float*)d_in[5];
    const float* bv = (const float*)d_in[6];
    float* out = (float*)d_out;

    float* ws = (float*)d_ws;
    const size_t NQ = (size_t)C * NPIX;       // 1M floats
    const size_t NS = (size_t)H * W * W;      // 2M floats

    float* qT   = ws;
    float* k    = ws + NQ;
    float* v    = ws + 2 * NQ;
    float* Sd   = ws + 3 * NQ;
    float* Vsum = ws + 3 * NQ + NS;

    k_conv<<<dim3(NPIX / 64, 2, 3), 256, 0, stream>>>(x, Wq, bq, Wk, bk, Wv, bv, qT, k, v);
    k_mid<<<dim3(1536), 256, 0, stream>>>(qT, k, v, Sd, Vsum);
    k_fused<<<dim3(H, 2), 1024, 0, stream>>>(Sd, Vsum, out);
}

// Round 8
// 123.025 us; speedup vs baseline: 1.0042x; 1.0042x over previous
//
#include <hip/hip_runtime.h>

static constexpr int C    = 64;
static constexpr int H    = 128;
static constexpr int W    = 128;
static constexpr int NPIX = H * W;      // 16384
static constexpr int PAD  = 3;          // WS=7 -> +-3

typedef float vf4 __attribute__((ext_vector_type(4)));   // NT-store-able

// ---------------------------------------------------------------------------
// 1) conv1x1, z-merged + non-temporal stores. Each wave: 64 pixels x
//    4 channels x {q,k,v} (12 acc chains) from ONE xr[64] register load.
//    grid (NPIX/64, 4) = 1024 blocks -> 4 blocks/CU, 16 waves/CU (4/SIMD).
//    x traffic 24 MB -> 16 MB. NT stores bypass the poison-dirty L2: no
//    write-allocate fetches, no new dirty lines for k_mid to evict.
//    (r4 lesson: W stays on the SMEM path, not LDS.)
// ---------------------------------------------------------------------------
__global__ __launch_bounds__(256, 4) void k_conv(
    const float* __restrict__ x,
    const float* __restrict__ Wq, const float* __restrict__ bq,
    const float* __restrict__ Wk, const float* __restrict__ bk,
    const float* __restrict__ Wv, const float* __restrict__ bv,
    float* __restrict__ qT, float* __restrict__ ko, float* __restrict__ vo)
{
    const int tid  = threadIdx.x;
    const int lane = tid & 63;
    const int p    = blockIdx.x * 64 + lane;
    const int o0   = __builtin_amdgcn_readfirstlane(
                         blockIdx.y * 16 + (tid >> 6) * 4);

    float xr[C];
#pragma unroll
    for (int c = 0; c < C; ++c) xr[c] = x[c * NPIX + p];

    float aq[4], ak[4], av[4];
#pragma unroll
    for (int j = 0; j < 4; ++j) {
        aq[j] = bq[o0 + j];
        ak[j] = bk[o0 + j];
        av[j] = bv[o0 + j];
    }

#pragma unroll
    for (int c = 0; c < C; ++c) {
        const float xv = xr[c];
#pragma unroll
        for (int j = 0; j < 4; ++j) {
            aq[j] += Wq[(o0 + j) * C + c] * xv;
            ak[j] += Wk[(o0 + j) * C + c] * xv;
            av[j] += Wv[(o0 + j) * C + c] * xv;
        }
    }

    vf4 qv4 = { aq[0], aq[1], aq[2], aq[3] };
    __builtin_nontemporal_store(qv4, (vf4*)(qT + (size_t)p * C + o0));
#pragma unroll
    for (int j = 0; j < 4; ++j) {
        __builtin_nontemporal_store(ak[j], ko + (size_t)(o0 + j) * NPIX + p);
        __builtin_nontemporal_store(av[j], vo + (size_t)(o0 + j) * NPIX + p);
    }
}

// ---------------------------------------------------------------------------
// 2) merged dispatch: [gram+diag] (blocks 0..1023) and [7x7 box of v]
//    (blocks 1024..1535). block 256.   [round-6 exact]
// ---------------------------------------------------------------------------
__global__ __launch_bounds__(256, 3) void k_mid(
    const float* __restrict__ qT, const float* __restrict__ kmat,
    const float* __restrict__ v,
    float* __restrict__ Sd, float* __restrict__ Vs)
{
    __shared__ union {
        struct { float Sl[22][130]; float qs[22][64]; } g;   // 16.7 KB
        struct { float vt[22][128]; float vh[22][128]; } box; // 22.5 KB
    } u;
    const int bid = blockIdx.x;
    const int tid = threadIdx.x;

    if (bid < 1024) {
        // ----- fused row-Gram + diagonal 7-sum -----
        const int h   = bid >> 3;
        const int w0  = (bid & 7) * 16;

        // stage q rows w0-3 .. w0+18 (zero-filled outside [0,W))
        for (int i = tid; i < 22 * 16; i += 256) {
            int r  = i >> 4, c4 = (i & 15) << 2;
            int wp = w0 - 3 + r;
            float4 qv = make_float4(0.f, 0.f, 0.f, 0.f);
            if (wp >= 0 && wp < W)
                qv = *(const float4*)(qT + (size_t)(h * W + wp) * C + c4);
            *(float4*)(&u.g.qs[r][c4]) = qv;
        }

        // two k-columns per thread: kkt and kkt+64 (coalesced loads)
        const int kkt = tid & 63;
        const int g   = tid >> 6;            // 0..3, wave-uniform row group
        float ks0[C], ks1[C];
#pragma unroll
        for (int c = 0; c < C; ++c) {
            ks0[c] = kmat[c * NPIX + h * W + kkt];
            ks1[c] = kmat[c * NPIX + h * W + kkt + 64];
        }
        __syncthreads();

        for (int j = 0; j < 6; ++j) {
            int row = g * 6 + j;             // 0..23, wave-uniform
            if (row < 22) {                  // wave-uniform branch
                float a0 = 0.f, a1 = 0.f, a2 = 0.f, a3 = 0.f;
                float b0 = 0.f, b1 = 0.f, b2 = 0.f, b3 = 0.f;
#pragma unroll
                for (int c = 0; c < C; c += 4) {
                    float4 qv = *(const float4*)(&u.g.qs[row][c]); // broadcast
                    a0 += qv.x * ks0[c + 0];  b0 += qv.x * ks1[c + 0];
                    a1 += qv.y * ks0[c + 1];  b1 += qv.y * ks1[c + 1];
                    a2 += qv.z * ks0[c + 2];  b2 += qv.z * ks1[c + 2];
                    a3 += qv.w * ks0[c + 3];  b3 += qv.w * ks1[c + 3];
                }
                u.g.Sl[row][kkt]      = (a0 + a1) + (a2 + a3);
                u.g.Sl[row][kkt + 64] = (b0 + b1) + (b2 + b3);
            }
        }
        __syncthreads();

        // ----- diagonal 7-sum (unchanged) -----
        const int kk  = tid & 127;
        const int wsl = tid >> 7;            // 0/1, wave-uniform
#pragma unroll
        for (int r = 0; r < 8; ++r) {
            int wl = wsl * 8 + r;            // 0..15
            float a = 0.f;
#pragma unroll
            for (int dd = -PAD; dd <= PAD; ++dd) {
                int kj = kk + dd;
                if (kj >= 0 && kj < W)
                    a += u.g.Sl[wl + 3 + dd][kj];
            }
            Sd[(size_t)(h * W + w0 + wl) * W + kk] = a;
        }
    } else {
        // ----- 7x7 box sum of v (separable in LDS, unchanged) -----
        const int b2 = bid - 1024;           // 0..511
        const int c  = b2 >> 3;              // 0..63
        const int h0 = (b2 & 7) * 16;

        for (int i = tid; i < 22 * 128; i += 256) {
            int r = i >> 7, w = i & 127;
            int h = h0 - 3 + r;
            u.box.vt[r][w] = (h >= 0 && h < H) ? v[c * NPIX + h * W + w] : 0.f;
        }
        __syncthreads();
        for (int i = tid; i < 22 * 128; i += 256) {
            int r = i >> 7, w = i & 127;
            float s = 0.f;
#pragma unroll
            for (int d = -PAD; d <= PAD; ++d) {
                int wj = w + d;
                if (wj >= 0 && wj < W) s += u.box.vt[r][wj];
            }
            u.box.vh[r][w] = s;
        }
        __syncthreads();
        for (int i = tid; i < 16 * 128; i += 256) {
            int r = i >> 7, w = i & 127;
            float s = 0.f;
#pragma unroll
            for (int d = 0; d < 7; ++d) s += u.box.vh[r + d][w];
            Vs[c * NPIX + (h0 + r) * W + w] = s;
        }
    }
}

// ---------------------------------------------------------------------------
// 3) FUSED vertical-7-sum + softmax + PV, 1024-thread version.  [r5 exact]
//    grid (H, 2) = 256 blocks x 1024 thr; 32 waves/CU. One barrier.
// ---------------------------------------------------------------------------
__global__ __launch_bounds__(1024, 4) void k_fused(
    const float* __restrict__ Sd, const float* __restrict__ Vs,
    float* __restrict__ out)
{
    constexpr int AP = 129;          // attn LDS pitch
    __shared__ float At[64][AP];     // attn[w-local][kk], 33.0 KB
    __shared__ float Vl[64][128];    // Vs[c][kk],         32.8 KB

    const int h   = blockIdx.x;
    const int w0  = blockIdx.y * 64;
    const int tid = threadIdx.x;

    // ---- issue Vs staging loads early (consumed after phase A) ----
    float4 vstage[2];
#pragma unroll
    for (int r = 0; r < 2; ++r) {
        int L  = tid + r * 1024;         // 0..2047 float4 tiles
        int c  = L >> 5;                 // 32 float4 per channel row
        int k4 = (L & 31) << 2;
        vstage[r] = *(const float4*)(Vs + (size_t)c * NPIX + h * W + k4);
    }

    // ---- phase A: logits (vertical 7-sum of Sd) + softmax into LDS ----
    const int wl = tid >> 4;             // 0..63 (w within half)
    const int s  = tid & 15;             // kk-16th: kk = s*8 + e

    float4 g0 = make_float4(0.f, 0.f, 0.f, 0.f);
    float4 g1 = g0;
#pragma unroll
    for (int i = 0; i < 7; ++i) {
        int hp = h - 3 + i;              // block-uniform branch
        if (hp >= 0 && hp < H) {
            const float4* src = (const float4*)(
                Sd + (size_t)hp * NPIX + (w0 + wl) * W + s * 8);
            float4 a = src[0], b = src[1];
            g0.x += a.x; g0.y += a.y; g0.z += a.z; g0.w += a.w;
            g1.x += b.x; g1.y += b.y; g1.z += b.z; g1.w += b.w;
        }
    }

    float lg[8] = { g0.x, g0.y, g0.z, g0.w,  g1.x, g1.y, g1.z, g1.w };

    float m = lg[0];
#pragma unroll
    for (int e = 1; e < 8; ++e) m = fmaxf(m, lg[e]);
#pragma unroll
    for (int off = 1; off <= 8; off <<= 1) m = fmaxf(m, __shfl_xor(m, off));

    float ssum = 0.f;
#pragma unroll
    for (int e = 0; e < 8; ++e) { lg[e] = __expf(lg[e] - m); ssum += lg[e]; }
#pragma unroll
    for (int off = 1; off <= 8; off <<= 1) ssum += __shfl_xor(ssum, off);
    const float inv = 1.f / ssum;

#pragma unroll
    for (int e = 0; e < 8; ++e) At[wl][s * 8 + e] = lg[e] * inv;

    // ---- land Vs into LDS, sync ----
#pragma unroll
    for (int r = 0; r < 2; ++r) {
        int L  = tid + r * 1024;
        int c  = L >> 5;
        int k4 = (L & 31) << 2;
        *(float4*)(&Vl[c][k4]) = vstage[r];
    }
    __syncthreads();

    // ---- phase B: out[c, h, w0+w2] = sum_kk At[w2][kk] * Vl[c][kk] ----
    const int w2 = tid & 63;
    const int c0 = __builtin_amdgcn_readfirstlane((tid >> 6) * 4);

    float acc[4];
#pragma unroll
    for (int j = 0; j < 4; ++j) acc[j] = 0.f;

    for (int kk = 0; kk < 128; kk += 4) {
        float4 a = *(const float4*)(&At[w2][kk]);
#pragma unroll
        for (int j = 0; j < 4; ++j) {
            float4 vv = *(const float4*)(&Vl[c0 + j][kk]);   // broadcast
            acc[j] += a.x * vv.x + a.y * vv.y + a.z * vv.z + a.w * vv.w;
        }
    }

#pragma unroll
    for (int j = 0; j < 4; ++j)
        out[(size_t)(c0 + j) * NPIX + h * W + w0 + w2] = acc[j];
}

// ---------------------------------------------------------------------------
// Workspace: 6M floats = 24 MB used, non-overlapping:
//   qT [0,1M)  k [1M,2M)  v [2M,3M)  Sd [3M,5M)  Vs [5M,6M)
// ---------------------------------------------------------------------------
extern "C" void kernel_launch(void* const* d_in, const int* in_sizes, int n_in,
                              void* d_out, int out_size, void* d_ws, size_t ws_size,
                              hipStream_t stream)
{
    const float* x  = (const float*)d_in[0];
    const float* Wq = (const float*)d_in[1];
    const float* bq = (const float*)d_in[2];
    const float* Wk = (const float*)d_in[3];
    const float* bk = (const float*)d_in[4];
    const float* Wv = (const float*)d_in[5];
    const float* bv = (const float*)d_in[6];
    float* out = (float*)d_out;

    float* ws = (float*)d_ws;
    const size_t NQ = (size_t)C * NPIX;       // 1M floats
    const size_t NS = (size_t)H * W * W;      // 2M floats

    float* qT   = ws;
    float* k    = ws + NQ;
    float* v    = ws + 2 * NQ;
    float* Sd   = ws + 3 * NQ;
    float* Vsum = ws + 3 * NQ + NS;

    k_conv<<<dim3(NPIX / 64, 4), 256, 0, stream>>>(x, Wq, bq, Wk, bk, Wv, bv, qT, k, v);
    k_mid<<<dim3(1536), 256, 0, stream>>>(qT, k, v, Sd, Vsum);
    k_fused<<<dim3(H, 2), 1024, 0, stream>>>(Sd, Vsum, out);
}